// Round 6
// baseline (799.583 us; speedup 1.0000x reference)
//
#include <hip/hip_runtime.h>

// Self-attention fwd: B=4, S=2048, D=1024, single head.
// Round 14: attack the LDS-traffic/lockstep limit found in R13 (3000 cyc per
// CU-K-tile = exact serial sum of MFMA 1241 + LDS-unit 1750).
//  (a) gemmW: 256x128 block, 4 waves, wave 128x64 (acc 8x4) -> LDS bytes per
//      FLOP drops 45.8 -> 34.3 B/KFLOP (traffic ~ wave perimeter).
//      BK=64 SINGLE-buffered LDS = 48 KB -> 3 blocks/CU, 12 waves/CU. The
//      per-tile vmcnt(0) latency is covered by the other 2 blocks.
//  (b) explicit stagger: slot=(lin%3) x s_sleep(512cyc) breaks the lockstep
//      that kept co-resident blocks phase-synced in R13 (both-read-then-
//      both-MFMA = serial sum; anti-phase = overlap, m114 mechanism).
//  (c) exact packing: QKV 768 blocks = 3x256 -> ONE pass (was 3 passes).
//      QK 512 (2/CU), VWo 256. PV keeps the proven R13 128x128 kernel
//      (512 blocks, 2/CU, double-buffered vmcnt(8)) + stagger.
//  Proven 128B-row XOR swizzle kept everywhere (conflicts measured 0).
//  Race-freedom of gemmW loop: stage(T) -> vmcnt(0)+barrier -> reads+MFMA ->
//  barrier -> stage(T+1). Every ds_read is consumed by an MFMA before the
//  second barrier, so next stage's async writes can't clobber live data.
//
// ws layout (bf16-element offsets over (u16*)d_ws):
//   xb    @ 0          (8388608)   <- VWoT after QKV (xb dead)  [b][do][s]
//   qkv   @ 8388608    (25165824)  [8192][3072] (q|k|v interleaved by col)
//   E     @ 33554432   (16777216)  exp(logits) bf16
//   wqkvT @ 50331648   (3145728)   [3072][1024]  (wqT|wkT|wvT)
//   woT   @ 53477376   (1048576)
//   bqkv  @ 54525952   (6144 u16 = 3072 fp32)
//   l     @ 54532096   (16384 u16 = 8192 fp32 row sums)   end = 109.1 MB

typedef unsigned short u16;
typedef short bf16x8 __attribute__((ext_vector_type(8)));
typedef float f32x4 __attribute__((ext_vector_type(4)));

#define SEQ 2048
#define DIM 1024

__device__ __forceinline__ u16 f2bf(float f) {
    unsigned u = __builtin_bit_cast(unsigned, f);
    u += 0x7fffu + ((u >> 16) & 1u);
    return (u16)(u >> 16);
}

// async 16B global -> LDS (wave-uniform LDS base + lane*16 by construction)
__device__ __forceinline__ void async16(void* lds, const void* gmem) {
    __builtin_amdgcn_global_load_lds(
        (const __attribute__((address_space(1))) void*)gmem,
        (__attribute__((address_space(3))) void*)lds, 16, 0, 0);
}

#define FENCE() asm volatile("" ::: "memory")

// ---------------------------------------------------------------------------
// cast x fp32 -> bf16 (blocks 0..8191); bias concat + zero l (blocks 8192+)
__global__ __launch_bounds__(256) void cast_x_kernel(
    const float* __restrict__ x, u16* __restrict__ xb,
    const float* __restrict__ bq, const float* __restrict__ bk,
    const float* __restrict__ bv, float* __restrict__ bqkv,
    float* __restrict__ l)
{
    const int b = blockIdx.x;
    if (b < 8192) {
        const int idx = b * 256 + threadIdx.x;
        float4 v = ((const float4*)x)[idx];
        ushort4 o;
        o.x = f2bf(v.x); o.y = f2bf(v.y); o.z = f2bf(v.z); o.w = f2bf(v.w);
        ((ushort4*)xb)[idx] = o;
    } else {
        const int i = (b - 8192) * 256 + threadIdx.x;   // 0..11263
        if (i < 3072)
            bqkv[i] = (i < 1024) ? bq[i] : (i < 2048) ? bk[i - 1024] : bv[i - 2048];
        else if (i < 3072 + 8192)
            l[i - 3072] = 0.f;
    }
}

// transpose+cast all four 1024x1024 fp32 weights -> bf16 WT[n][k]; z picks W.
__global__ __launch_bounds__(256) void transpose_cast_all(
    const float* __restrict__ W0, const float* __restrict__ W1,
    const float* __restrict__ W2, const float* __restrict__ W3,
    u16* __restrict__ Tqkv, u16* __restrict__ To)
{
    __shared__ float tile[32][33];
    const int z = blockIdx.z;
    const float* W = (z == 0) ? W0 : (z == 1) ? W1 : (z == 2) ? W2 : W3;
    u16* T = (z < 3) ? (Tqkv + (size_t)z * 1048576) : To;

    const int bx = blockIdx.x * 32, by = blockIdx.y * 32;
    const int tx = threadIdx.x, ty = threadIdx.y;
    #pragma unroll
    for (int r = 0; r < 4; ++r)
        tile[ty + r * 8][tx] = W[(size_t)(by + ty + r * 8) * DIM + bx + tx];
    __syncthreads();
    #pragma unroll
    for (int r = 0; r < 4; ++r) {
        const float v = tile[tx][ty + r * 8];   // = W[by+tx][bx+ty+r*8]
        T[(size_t)(bx + ty + r * 8) * DIM + by + tx] = f2bf(v);
    }
}

// ---------------------------------------------------------------------------
#define EPI_BF16BIAS 0  // bf16 store of a+bias[col]
#define EPI_BF16     1  // bf16 store of a
#define EPI_ELOGIT   2  // store exp(a*scale) bf16 + atomic row sums into lsum
#define EPI_PVOUT    3  // fp32 store of a/lsum[row] + bias[col]

// ---------------------------------------------------------------------------
// gemmW: 256x128-tile, 4 waves, wave 128x64 (acc 8x4), BK=64 single-buffered
// LDS (48 KB -> 3 blocks/CU). A[M,K] @ Bt[N,K]^T.
template<int EPI, int K, int LDA, int LDB, int LDC>
__global__ __launch_bounds__(256, 3) void gemmW(
    const u16* __restrict__ A, const u16* __restrict__ Bt,
    const float* __restrict__ bias, u16* __restrict__ C,
    float* __restrict__ Cf, float* __restrict__ lsum,
    float scale, long sA, long sB, long sC)
{
    __shared__ u16 sAt[256 * 64];   // 32 KB
    __shared__ u16 sBt[128 * 64];   // 16 KB

    constexpr int NT = K / 64;

    const int z = blockIdx.z;
    const int t = threadIdx.x;                 // 0..255
    const int wid = t >> 6, lane = t & 63;
    const int wm = wid >> 1, wn = wid & 1;     // wave tile: 128x64 at (wm,wn)
    const int lrow = lane & 15, quad = lane >> 4;
    const int m0 = blockIdx.y * 256, n0 = blockIdx.x * 128;

    // anti-lockstep stagger: ~0/512/1024 cyc by residency slot
    const int lin = blockIdx.x + gridDim.x * (blockIdx.y + gridDim.y * z);
    const int slot = lin % 3;
    if (slot > 0) __builtin_amdgcn_s_sleep(8);
    if (slot > 1) __builtin_amdgcn_s_sleep(8);

    const u16* ABase = A  + (size_t)z * sA + (size_t)m0 * LDA;
    const u16* BBase = Bt + (size_t)z * sB + (size_t)n0 * LDB;

    // staging: A 2048 16B-chunks (8/thread), B 1024 (4/thread). LDS dest is
    // linear; global SOURCE chunk is pre-swizzled with the read involution
    // chunk ^= (row&7)  (byte bits 4-6 ^= row bits 0-2; rows are 128 B).
    int offA[8], offB[4];
    #pragma unroll
    for (int p = 0; p < 8; ++p) {
        const int s = p * 256 + t, row = s >> 3, c8 = (s & 7) ^ (row & 7);
        offA[p] = row * LDA + c8 * 8;
    }
    #pragma unroll
    for (int p = 0; p < 4; ++p) {
        const int s = p * 256 + t, row = s >> 3, c8 = (s & 7) ^ (row & 7);
        offB[p] = row * LDB + c8 * 8;
    }

    f32x4 acc[8][4];
    #pragma unroll
    for (int i = 0; i < 8; ++i)
        #pragma unroll
        for (int j = 0; j < 4; ++j)
            acc[i][j] = (f32x4){0.f, 0.f, 0.f, 0.f};

    auto ldA1 = [&](int mi, int ks) -> bf16x8 {
        int b = (wm * 128 + mi * 16 + lrow) * 128 + ks * 64 + quad * 16;
        b ^= ((b >> 7) & 7) << 4;
        return *(const bf16x8*)((const char*)sAt + b);
    };
    auto ldB1 = [&](int ni, int ks) -> bf16x8 {
        int b = (wn * 64 + ni * 16 + lrow) * 128 + ks * 64 + quad * 16;
        b ^= ((b >> 7) & 7) << 4;
        return *(const bf16x8*)((const char*)sBt + b);
    };

    #pragma unroll 1
    for (int T = 0; T < NT; ++T) {
        const int k0 = T * 64;
        #pragma unroll
        for (int p = 0; p < 8; ++p)
            async16(&sAt[(p * 256 + t) * 8], ABase + k0 + offA[p]);
        #pragma unroll
        for (int p = 0; p < 4; ++p)
            async16(&sBt[(p * 256 + t) * 8], BBase + k0 + offB[p]);
        asm volatile("s_waitcnt vmcnt(0)" ::: "memory");
        __builtin_amdgcn_s_barrier();

        #pragma unroll
        for (int ks = 0; ks < 2; ++ks) {
            bf16x8 aF[8], bF[4];
            #pragma unroll
            for (int mi = 0; mi < 8; ++mi) aF[mi] = ldA1(mi, ks);
            #pragma unroll
            for (int ni = 0; ni < 4; ++ni) bF[ni] = ldB1(ni, ks);
            __builtin_amdgcn_s_setprio(1);
            #pragma unroll
            for (int mi = 0; mi < 8; ++mi)
                #pragma unroll
                for (int ni = 0; ni < 4; ++ni)
                    acc[mi][ni] = __builtin_amdgcn_mfma_f32_16x16x32_bf16(
                        aF[mi], bF[ni], acc[mi][ni], 0, 0, 0);
            __builtin_amdgcn_s_setprio(0);
        }
        FENCE();
        __builtin_amdgcn_s_barrier();  // all reads consumed -> next stage safe
    }

    // ---- epilogue ----
    u16*   Cz  = C  + (size_t)z * sC;
    float* Cfz = Cf ? Cf + (size_t)z * sC : nullptr;

    #pragma unroll
    for (int mi = 0; mi < 8; ++mi) {
        const int row = m0 + wm * 128 + mi * 16 + quad * 4;  // rows row..row+3
        if (EPI == EPI_BF16BIAS) {
            #pragma unroll
            for (int ni = 0; ni < 4; ++ni) {
                const int col = n0 + wn * 64 + ni * 16 + lrow;
                const float bb = bias[col];
                const f32x4 a = acc[mi][ni];
                #pragma unroll
                for (int r = 0; r < 4; ++r)
                    Cz[(size_t)(row + r) * LDC + col] = f2bf(a[r] + bb);
            }
        } else if (EPI == EPI_BF16) {
            #pragma unroll
            for (int ni = 0; ni < 4; ++ni) {
                const int col = n0 + wn * 64 + ni * 16 + lrow;
                const f32x4 a = acc[mi][ni];
                #pragma unroll
                for (int r = 0; r < 4; ++r)
                    Cz[(size_t)(row + r) * LDC + col] = f2bf(a[r]);
            }
        } else if (EPI == EPI_ELOGIT) {
            float rs[4] = {0.f, 0.f, 0.f, 0.f};
            #pragma unroll
            for (int ni = 0; ni < 4; ++ni) {
                const int col = n0 + wn * 64 + ni * 16 + lrow;
                const f32x4 a = acc[mi][ni];
                #pragma unroll
                for (int r = 0; r < 4; ++r) {
                    const float e = __expf(a[r] * scale);
                    Cz[(size_t)(row + r) * LDC + col] = f2bf(e);
                    rs[r] += e;
                }
            }
            #pragma unroll
            for (int r = 0; r < 4; ++r) {
                float s = rs[r];
                s += __shfl_xor(s, 1, 64);
                s += __shfl_xor(s, 2, 64);
                s += __shfl_xor(s, 4, 64);
                s += __shfl_xor(s, 8, 64);
                if (lrow == 0)
                    atomicAdd(&lsum[(size_t)z * 2048 + row + r], s);
            }
        } else { // EPI_PVOUT (unused in gemmW dispatches, kept for symmetry)
            float linv[4];
            #pragma unroll
            for (int r = 0; r < 4; ++r)
                linv[r] = 1.0f / lsum[(size_t)z * 2048 + row + r];
            #pragma unroll
            for (int ni = 0; ni < 4; ++ni) {
                const int col = n0 + wn * 64 + ni * 16 + lrow;
                const float bb = bias[col];
                const f32x4 a = acc[mi][ni];
                #pragma unroll
                for (int r = 0; r < 4; ++r)
                    Cfz[(size_t)(row + r) * LDC + col] = a[r] * linv[r] + bb;
            }
        }
    }
}

// ---------------------------------------------------------------------------
// gemm4w: R13's proven 128x128-tile 4-wave kernel (2 blocks/CU, BK=64
// double-buffered, counted vmcnt(8)) + parity stagger. Used for PV.
template<int EPI, int K, int LDA, int LDB, int LDC>
__global__ __launch_bounds__(256, 2) void gemm4w(
    const u16* __restrict__ A, const u16* __restrict__ Bt,
    const float* __restrict__ bias, u16* __restrict__ C,
    float* __restrict__ Cf, float* __restrict__ lsum,
    float scale, long sA, long sB, long sC)
{
    __shared__ u16 lds[2][2][8192];   // [dbuf][A/B][128x64], 64 KiB

    constexpr int NT = K / 64;

    const int z = blockIdx.z;
    const int t = threadIdx.x;                 // 0..255
    const int wid = t >> 6, lane = t & 63;
    const int wm = wid >> 1, wn = wid & 1;     // wave tile: 64x64 at (wm,wn)
    const int lrow = lane & 15, quad = lane >> 4;
    const int m0 = blockIdx.y * 128, n0 = blockIdx.x * 128;

    const int lin = blockIdx.x + gridDim.x * (blockIdx.y + gridDim.y * z);
    if (lin & 1) __builtin_amdgcn_s_sleep(8);

    const u16* ABase = A  + (size_t)z * sA + (size_t)m0 * LDA;
    const u16* BBase = Bt + (size_t)z * sB + (size_t)n0 * LDB;

    int srow[4], scolOff[4];
    #pragma unroll
    for (int p = 0; p < 4; ++p) {
        const int s = p * 256 + t, row = s >> 3, c8 = (s & 7) ^ (row & 7);
        srow[p] = row; scolOff[p] = c8 * 8;
    }

    auto stage = [&](int tile, int buf) {
        const int k0 = tile * 64;
        #pragma unroll
        for (int p = 0; p < 4; ++p) {
            const int s = p * 256 + t;
            async16(&lds[buf][0][s * 8],
                    ABase + (size_t)srow[p] * LDA + k0 + scolOff[p]);
        }
        #pragma unroll
        for (int p = 0; p < 4; ++p) {
            const int s = p * 256 + t;
            async16(&lds[buf][1][s * 8],
                    BBase + (size_t)srow[p] * LDB + k0 + scolOff[p]);
        }
    };

    f32x4 acc[4][4];
    #pragma unroll
    for (int i = 0; i < 4; ++i)
        #pragma unroll
        for (int j = 0; j < 4; ++j)
            acc[i][j] = (f32x4){0.f, 0.f, 0.f, 0.f};

    auto ldA1 = [&](int buf, int mi, int ks) -> bf16x8 {
        int b = (wm * 64 + mi * 16 + lrow) * 128 + ks * 64 + quad * 16;
        b ^= ((b >> 7) & 7) << 4;
        return *(const bf16x8*)((const char*)&lds[buf][0][0] + b);
    };
    auto ldB1 = [&](int buf, int ni, int ks) -> bf16x8 {
        int b = (wn * 64 + ni * 16 + lrow) * 128 + ks * 64 + quad * 16;
        b ^= ((b >> 7) & 7) << 4;
        return *(const bf16x8*)((const char*)&lds[buf][1][0] + b);
    };

    stage(0, 0);
    stage(1, 1);

    #pragma unroll 1
    for (int T = 0; T < NT; ++T) {
        const int buf = T & 1;
        if (T + 1 < NT) asm volatile("s_waitcnt vmcnt(8)" ::: "memory");
        else            asm volatile("s_waitcnt vmcnt(0)" ::: "memory");
        __builtin_amdgcn_s_barrier();

        #pragma unroll
        for (int ks = 0; ks < 2; ++ks) {
            bf16x8 aF[4], bF[4];
            #pragma unroll
            for (int mi = 0; mi < 4; ++mi) aF[mi] = ldA1(buf, mi, ks);
            #pragma unroll
            for (int ni = 0; ni < 4; ++ni) bF[ni] = ldB1(buf, ni, ks);
            __builtin_amdgcn_s_setprio(1);
            #pragma unroll
            for (int mi = 0; mi < 4; ++mi)
                #pragma unroll
                for (int ni = 0; ni < 4; ++ni)
                    acc[mi][ni] = __builtin_amdgcn_mfma_f32_16x16x32_bf16(
                        aF[mi], bF[ni], acc[mi][ni], 0, 0, 0);
            __builtin_amdgcn_s_setprio(0);
        }
        FENCE();
        __builtin_amdgcn_s_barrier();
        if (T + 2 < NT) stage(T + 2, buf);
    }

    u16*   Cz  = C  + (size_t)z * sC;
    float* Cfz = Cf ? Cf + (size_t)z * sC : nullptr;

    #pragma unroll
    for (int mi = 0; mi < 4; ++mi) {
        const int row = m0 + wm * 64 + mi * 16 + quad * 4;
        if (EPI == EPI_PVOUT) {
            float linv[4];
            #pragma unroll
            for (int r = 0; r < 4; ++r)
                linv[r] = 1.0f / lsum[(size_t)z * 2048 + row + r];
            #pragma unroll
            for (int ni = 0; ni < 4; ++ni) {
                const int col = n0 + wn * 64 + ni * 16 + lrow;
                const float bb = bias[col];
                const f32x4 a = acc[mi][ni];
                #pragma unroll
                for (int r = 0; r < 4; ++r)
                    Cfz[(size_t)(row + r) * LDC + col] = a[r] * linv[r] + bb;
            }
        } else { // EPI_BF16 fallback (unused here)
            #pragma unroll
            for (int ni = 0; ni < 4; ++ni) {
                const int col = n0 + wn * 64 + ni * 16 + lrow;
                const f32x4 a = acc[mi][ni];
                #pragma unroll
                for (int r = 0; r < 4; ++r)
                    Cz[(size_t)(row + r) * LDC + col] = f2bf(a[r]);
            }
        }
    }
}

// ---------------------------------------------------------------------------
extern "C" void kernel_launch(void* const* d_in, const int* in_sizes, int n_in,
                              void* d_out, int out_size, void* d_ws, size_t ws_size,
                              hipStream_t stream)
{
    const float* x  = (const float*)d_in[0];
    const float* wq = (const float*)d_in[1];
    const float* bq = (const float*)d_in[2];
    const float* wk = (const float*)d_in[3];
    const float* bk = (const float*)d_in[4];
    const float* wv = (const float*)d_in[5];
    const float* bv = (const float*)d_in[6];
    const float* wo = (const float*)d_in[7];
    const float* bo = (const float*)d_in[8];
    float* out = (float*)d_out;

    u16* w16   = (u16*)d_ws;
    u16* xb    = w16;
    u16* qkv   = w16 + 8388608;          // [8192][3072]; q|k|v at col 0/1024/2048
    u16* E     = w16 + 33554432;
    u16* wqkvT = w16 + 50331648;         // [3072][1024] = wqT|wkT|wvT
    u16* woT   = w16 + 53477376;
    float* bqkv = (float*)(w16 + 54525952);
    float* l    = (float*)(w16 + 54532096);
    u16* VWoT  = w16;                    // aliases xb (dead after QKV) [b][1024][2048]

    const u16* q_ = qkv;                 // LDA/LDB = 3072 views
    const u16* k_ = qkv + 1024;
    const u16* v_ = qkv + 2048;

    cast_x_kernel<<<8236, dim3(256), 0, stream>>>(x, xb, bq, bk, bv, bqkv, l);
    transpose_cast_all<<<dim3(32, 32, 4), dim3(32, 8), 0, stream>>>(
        wq, wk, wv, wo, wqkvT, woT);

    // fused QKV: qkv[8192,3072] = xb @ wqkvT^T + bqkv  (24x32 = 768 blk, 1 pass)
    gemmW<EPI_BF16BIAS, 1024, 1024, 1024, 3072>
        <<<dim3(24, 32, 1), dim3(256), 0, stream>>>(
            xb, wqkvT, bqkv, qkv, nullptr, nullptr, 1.f, 0, 0, 0);

    // E[z] = exp((q[z] @ k[z]^T)/32) bf16, + row sums into l  (512 blocks)
    gemmW<EPI_ELOGIT, 1024, 3072, 3072, 2048>
        <<<dim3(16, 8, 4), dim3(256), 0, stream>>>(
            q_, k_, nullptr, E, nullptr, l, 0.03125f,
            6291456, 6291456, 4194304);

    // VWoT[z] = woT @ v[z]^T   [1024][2048] bf16 per batch  (256 blocks)
    gemmW<EPI_BF16, 1024, 1024, 3072, 2048>
        <<<dim3(16, 4, 4), dim3(256), 0, stream>>>(
            woT, v_, nullptr, VWoT, nullptr, nullptr, 1.f,
            0, 6291456, 2097152);

    // out[z] = (E[z] @ VWoT[z]^T) / l + bo   fp32 [2048][1024]  (512 blocks)
    gemm4w<EPI_PVOUT, 2048, 2048, 2048, 1024>
        <<<dim3(8, 16, 4), dim3(256), 0, stream>>>(
            E, VWoT, bo, nullptr, out, l, 1.f,
            4194304, 2097152, 2097152);
}

// Round 7
// 308.488 us; speedup vs baseline: 2.5919x; 2.5919x over previous
//
#include <hip/hip_runtime.h>

// Self-attention fwd: B=4, S=2048, D=1024, single head.
// Round 15: revert R14 (1-pass packing destroyed L2 locality: FETCH 77->462MB,
// fetch-bound at 277us). Back to R13 (best passing, 273.9us) + ONE change:
// within-wave register read-ahead pipeline in the K-loop.
//   R13 measured 3000 cyc/CU-K-tile = LDS(1500) + MFMA(1241) serial even at
//   2 blocks/CU: fair LDS round-robin serves all 8 waves evenly, so all finish
//   reads together, then all MFMA together - no cross-wave overlap. Fix that
//   does not rely on arbitration: double frag registers, read tile T+1's
//   fragments WHILE MFMA-ing tile T's (in-wave ILP):
//     step T: vmcnt(0; queue = T+1's 8 loads) -> bar
//             -> issue ds_reads(frags T+1)  [overlap]
//             -> MFMA(frags T)              [overlap]
//             -> bar -> stage(T+2 -> buf[T&1])
//   Race-free: MFMA(T) issue implies its tile-T reads drained (lgkmcnt), so
//   post-MFMA bar means ALL waves' tile-T reads done before stage overwrites
//   buf[T&1]; in-flight reads at that bar target buf[(T+1)&1] (other buffer).
//   Frag sets ping-pong with STATIC names (runtime-indexed arrays -> scratch).
// Everything else identical to R13 (grids, epilogues, swizzle, ws layout).
//
// ws layout (bf16-element offsets over (u16*)d_ws):
//   xb    @ 0          (8388608)   <- VWoT after QKV (xb dead)  [b][do][s]
//   qkv   @ 8388608    (25165824)  [8192][3072] (q|k|v interleaved by col)
//   E     @ 33554432   (16777216)  exp(logits) bf16
//   wqkvT @ 50331648   (3145728)   [3072][1024]  (wqT|wkT|wvT)
//   woT   @ 53477376   (1048576)
//   bqkv  @ 54525952   (6144 u16 = 3072 fp32)
//   l     @ 54532096   (16384 u16 = 8192 fp32 row sums)   end = 109.1 MB

typedef unsigned short u16;
typedef short bf16x8 __attribute__((ext_vector_type(8)));
typedef float f32x4 __attribute__((ext_vector_type(4)));

#define SEQ 2048
#define DIM 1024

__device__ __forceinline__ u16 f2bf(float f) {
    unsigned u = __builtin_bit_cast(unsigned, f);
    u += 0x7fffu + ((u >> 16) & 1u);
    return (u16)(u >> 16);
}

// async 16B global -> LDS (wave-uniform LDS base + lane*16 by construction)
__device__ __forceinline__ void async16(void* lds, const void* gmem) {
    __builtin_amdgcn_global_load_lds(
        (const __attribute__((address_space(1))) void*)gmem,
        (__attribute__((address_space(3))) void*)lds, 16, 0, 0);
}

#define FENCE() asm volatile("" ::: "memory")

// ---------------------------------------------------------------------------
// cast x fp32 -> bf16 (blocks 0..8191); bias concat + zero l (blocks 8192+)
__global__ __launch_bounds__(256) void cast_x_kernel(
    const float* __restrict__ x, u16* __restrict__ xb,
    const float* __restrict__ bq, const float* __restrict__ bk,
    const float* __restrict__ bv, float* __restrict__ bqkv,
    float* __restrict__ l)
{
    const int b = blockIdx.x;
    if (b < 8192) {
        const int idx = b * 256 + threadIdx.x;
        float4 v = ((const float4*)x)[idx];
        ushort4 o;
        o.x = f2bf(v.x); o.y = f2bf(v.y); o.z = f2bf(v.z); o.w = f2bf(v.w);
        ((ushort4*)xb)[idx] = o;
    } else {
        const int i = (b - 8192) * 256 + threadIdx.x;   // 0..11263
        if (i < 3072)
            bqkv[i] = (i < 1024) ? bq[i] : (i < 2048) ? bk[i - 1024] : bv[i - 2048];
        else if (i < 3072 + 8192)
            l[i - 3072] = 0.f;
    }
}

// transpose+cast all four 1024x1024 fp32 weights -> bf16 WT[n][k]; z picks W.
__global__ __launch_bounds__(256) void transpose_cast_all(
    const float* __restrict__ W0, const float* __restrict__ W1,
    const float* __restrict__ W2, const float* __restrict__ W3,
    u16* __restrict__ Tqkv, u16* __restrict__ To)
{
    __shared__ float tile[32][33];
    const int z = blockIdx.z;
    const float* W = (z == 0) ? W0 : (z == 1) ? W1 : (z == 2) ? W2 : W3;
    u16* T = (z < 3) ? (Tqkv + (size_t)z * 1048576) : To;

    const int bx = blockIdx.x * 32, by = blockIdx.y * 32;
    const int tx = threadIdx.x, ty = threadIdx.y;
    #pragma unroll
    for (int r = 0; r < 4; ++r)
        tile[ty + r * 8][tx] = W[(size_t)(by + ty + r * 8) * DIM + bx + tx];
    __syncthreads();
    #pragma unroll
    for (int r = 0; r < 4; ++r) {
        const float v = tile[tx][ty + r * 8];   // = W[by+tx][bx+ty+r*8]
        T[(size_t)(bx + ty + r * 8) * DIM + by + tx] = f2bf(v);
    }
}

// ---------------------------------------------------------------------------
// 128x128-tile 4-wave GEMM: A[M,K] @ Bt[N,K]^T. 2 blocks/CU (64 KiB LDS).
// K-loop: register read-ahead pipeline (see header comment).
#define EPI_BF16BIAS 0  // bf16 store of a+bias[col]
#define EPI_BF16     1  // bf16 store of a
#define EPI_ELOGIT   2  // store exp(a*scale) bf16 + atomic row sums into lsum
#define EPI_PVOUT    3  // fp32 store of a/lsum[row] + bias[col]

template<int EPI, int K, int LDA, int LDB, int LDC>
__global__ __launch_bounds__(256, 2) void gemm4w(
    const u16* __restrict__ A, const u16* __restrict__ Bt,
    const float* __restrict__ bias, u16* __restrict__ C,
    float* __restrict__ Cf, float* __restrict__ lsum,
    float scale, long sA, long sB, long sC)
{
    // [dbuf][mat(A/B)][128x64 bf16], 16 KB each = 64 KiB total.
    __shared__ u16 lds[2][2][8192];

    constexpr int NT = K / 64;      // 64-wide K tiles (even, >= 4)
    static_assert(NT % 2 == 0 && NT >= 4, "NT even");

    const int z = blockIdx.z;
    const int t = threadIdx.x;                 // 0..255
    const int wid = t >> 6, lane = t & 63;
    const int wm = wid >> 1, wn = wid & 1;     // wave tile: 64x64 at (wm,wn)
    const int lrow = lane & 15, quad = lane >> 4;
    const int m0 = blockIdx.y * 128, n0 = blockIdx.x * 128;

    const u16* ABase = A  + (size_t)z * sA + (size_t)m0 * LDA;
    const u16* BBase = Bt + (size_t)z * sB + (size_t)n0 * LDB;

    // staging: 1024 16B chunks per 128x64 tile; thread owns 4 per mat. LDS
    // dest linear (global_load_lds constraint); global SOURCE chunk column is
    // pre-swizzled with the read involution chunk ^= (row&7)
    // (byte bits 4-6 ^= row bits 0-2; rows are 128 B).
    int srow[4], scolOff[4];
    #pragma unroll
    for (int p = 0; p < 4; ++p) {
        const int s = p * 256 + t, row = s >> 3, c8 = (s & 7) ^ (row & 7);
        srow[p] = row; scolOff[p] = c8 * 8;
    }

    auto stage = [&](int tile, int buf) {
        const int k0 = tile * 64;
        #pragma unroll
        for (int p = 0; p < 4; ++p) {
            const int s = p * 256 + t;
            async16(&lds[buf][0][s * 8],
                    ABase + (size_t)srow[p] * LDA + k0 + scolOff[p]);
        }
        #pragma unroll
        for (int p = 0; p < 4; ++p) {
            const int s = p * 256 + t;
            async16(&lds[buf][1][s * 8],
                    BBase + (size_t)srow[p] * LDB + k0 + scolOff[p]);
        }
    };

    f32x4 acc[4][4];
    #pragma unroll
    for (int i = 0; i < 4; ++i)
        #pragma unroll
        for (int j = 0; j < 4; ++j)
            acc[i][j] = (f32x4){0.f, 0.f, 0.f, 0.f};

    // swizzled ds_read of one 16x16x32 fragment (16B per lane); ks in {0,1}
    auto ldA1 = [&](int buf, int mi, int ks) -> bf16x8 {
        int b = (wm * 64 + mi * 16 + lrow) * 128 + ks * 64 + quad * 16;
        b ^= ((b >> 7) & 7) << 4;
        return *(const bf16x8*)((const char*)&lds[buf][0][0] + b);
    };
    auto ldB1 = [&](int buf, int ni, int ks) -> bf16x8 {
        int b = (wn * 64 + ni * 16 + lrow) * 128 + ks * 64 + quad * 16;
        b ^= ((b >> 7) & 7) << 4;
        return *(const bf16x8*)((const char*)&lds[buf][1][0] + b);
    };

    // two static frag sets (ping-pong; runtime index would go to scratch)
    bf16x8 a0[4][2], b0[4][2], a1[4][2], b1[4][2];

    auto readFrags = [&](int buf, bf16x8 (&aF)[4][2], bf16x8 (&bF)[4][2]) {
        #pragma unroll
        for (int ks = 0; ks < 2; ++ks) {
            #pragma unroll
            for (int mi = 0; mi < 4; ++mi) aF[mi][ks] = ldA1(buf, mi, ks);
            #pragma unroll
            for (int ni = 0; ni < 4; ++ni) bF[ni][ks] = ldB1(buf, ni, ks);
        }
    };
    auto mfmaAll = [&](bf16x8 (&aF)[4][2], bf16x8 (&bF)[4][2]) {
        __builtin_amdgcn_s_setprio(1);
        #pragma unroll
        for (int ks = 0; ks < 2; ++ks)
            #pragma unroll
            for (int mi = 0; mi < 4; ++mi)
                #pragma unroll
                for (int ni = 0; ni < 4; ++ni)
                    acc[mi][ni] = __builtin_amdgcn_mfma_f32_16x16x32_bf16(
                        aF[mi][ks], bF[ni][ks], acc[mi][ni], 0, 0, 0);
        __builtin_amdgcn_s_setprio(0);
    };

    // one pipeline step: frags(T) already in cur; reads frags(T+1) into nxt
    // while MFMA-ing cur; then stages T+2 into buf[T&1].
    auto step = [&](int T, bf16x8 (&cA)[4][2], bf16x8 (&cB)[4][2],
                           bf16x8 (&nA)[4][2], bf16x8 (&nB)[4][2]) {
        if (T + 1 < NT) {
            // queue holds only tile T+1's 8 loads -> this waits exactly them
            asm volatile("s_waitcnt vmcnt(0)" ::: "memory");
            __builtin_amdgcn_s_barrier();
            readFrags((T + 1) & 1, nA, nB);      // issue; overlaps MFMA below
        }
        mfmaAll(cA, cB);
        FENCE();
        __builtin_amdgcn_s_barrier();            // all tile-T reads consumed
        if (T + 2 < NT) stage(T + 2, T & 1);     // overwrite buf[T&1] safely
    };

    // ---- prologue: tiles 0,1 staged; frags(0) in a0/b0 ----
    stage(0, 0);
    stage(1, 1);
    asm volatile("s_waitcnt vmcnt(8)" ::: "memory");   // tile0 landed
    __builtin_amdgcn_s_barrier();
    readFrags(0, a0, b0);

    #pragma unroll 1
    for (int T = 0; T < NT; T += 2) {
        step(T,     a0, b0, a1, b1);
        step(T + 1, a1, b1, a0, b0);
    }

    // ---- epilogue ----
    u16*   Cz  = C  + (size_t)z * sC;
    float* Cfz = Cf ? Cf + (size_t)z * sC : nullptr;

    #pragma unroll
    for (int mi = 0; mi < 4; ++mi) {
        const int row = m0 + wm * 64 + mi * 16 + quad * 4;   // rows row..row+3
        if (EPI == EPI_BF16BIAS) {
            #pragma unroll
            for (int ni = 0; ni < 4; ++ni) {
                const int col = n0 + wn * 64 + ni * 16 + lrow;
                const float bb = bias[col];
                const f32x4 a = acc[mi][ni];
                #pragma unroll
                for (int r = 0; r < 4; ++r)
                    Cz[(size_t)(row + r) * LDC + col] = f2bf(a[r] + bb);
            }
        } else if (EPI == EPI_BF16) {
            #pragma unroll
            for (int ni = 0; ni < 4; ++ni) {
                const int col = n0 + wn * 64 + ni * 16 + lrow;
                const f32x4 a = acc[mi][ni];
                #pragma unroll
                for (int r = 0; r < 4; ++r)
                    Cz[(size_t)(row + r) * LDC + col] = f2bf(a[r]);
            }
        } else if (EPI == EPI_ELOGIT) {
            float rs[4] = {0.f, 0.f, 0.f, 0.f};
            #pragma unroll
            for (int ni = 0; ni < 4; ++ni) {
                const int col = n0 + wn * 64 + ni * 16 + lrow;
                const f32x4 a = acc[mi][ni];
                #pragma unroll
                for (int r = 0; r < 4; ++r) {
                    const float e = __expf(a[r] * scale);
                    Cz[(size_t)(row + r) * LDC + col] = f2bf(e);
                    rs[r] += e;
                }
            }
            #pragma unroll
            for (int r = 0; r < 4; ++r) {
                float s = rs[r];
                s += __shfl_xor(s, 1, 64);
                s += __shfl_xor(s, 2, 64);
                s += __shfl_xor(s, 4, 64);
                s += __shfl_xor(s, 8, 64);
                if (lrow == 0)
                    atomicAdd(&lsum[(size_t)z * 2048 + row + r], s);
            }
        } else { // EPI_PVOUT
            float linv[4];
            #pragma unroll
            for (int r = 0; r < 4; ++r)
                linv[r] = 1.0f / lsum[(size_t)z * 2048 + row + r];
            #pragma unroll
            for (int ni = 0; ni < 4; ++ni) {
                const int col = n0 + wn * 64 + ni * 16 + lrow;
                const float bb = bias[col];
                const f32x4 a = acc[mi][ni];
                #pragma unroll
                for (int r = 0; r < 4; ++r)
                    Cfz[(size_t)(row + r) * LDC + col] = a[r] * linv[r] + bb;
            }
        }
    }
}

// ---------------------------------------------------------------------------
extern "C" void kernel_launch(void* const* d_in, const int* in_sizes, int n_in,
                              void* d_out, int out_size, void* d_ws, size_t ws_size,
                              hipStream_t stream)
{
    const float* x  = (const float*)d_in[0];
    const float* wq = (const float*)d_in[1];
    const float* bq = (const float*)d_in[2];
    const float* wk = (const float*)d_in[3];
    const float* bk = (const float*)d_in[4];
    const float* wv = (const float*)d_in[5];
    const float* bv = (const float*)d_in[6];
    const float* wo = (const float*)d_in[7];
    const float* bo = (const float*)d_in[8];
    float* out = (float*)d_out;

    u16* w16   = (u16*)d_ws;
    u16* xb    = w16;
    u16* qkv   = w16 + 8388608;          // [8192][3072]; q|k|v at col 0/1024/2048
    u16* E     = w16 + 33554432;
    u16* wqkvT = w16 + 50331648;         // [3072][1024] = wqT|wkT|wvT
    u16* woT   = w16 + 53477376;
    float* bqkv = (float*)(w16 + 54525952);
    float* l    = (float*)(w16 + 54532096);
    u16* VWoT  = w16;                    // aliases xb (dead after QKV) [b][1024][2048]

    const u16* q_ = qkv;                 // LDA/LDB = 3072 views
    const u16* k_ = qkv + 1024;
    const u16* v_ = qkv + 2048;

    cast_x_kernel<<<8236, dim3(256), 0, stream>>>(x, xb, bq, bk, bv, bqkv, l);
    transpose_cast_all<<<dim3(32, 32, 4), dim3(32, 8), 0, stream>>>(
        wq, wk, wv, wo, wqkvT, woT);

    // fused QKV: qkv[8192,3072] = xb @ wqkvT^T + bqkv   (24x64 = 1536 blocks)
    gemm4w<EPI_BF16BIAS, 1024, 1024, 1024, 3072>
        <<<dim3(24, 64, 1), dim3(256), 0, stream>>>(
            xb, wqkvT, bqkv, qkv, nullptr, nullptr, 1.f, 0, 0, 0);

    // E[z] = exp((q[z] @ k[z]^T)/32) bf16, + row sums into l  (1024 blocks)
    gemm4w<EPI_ELOGIT, 1024, 3072, 3072, 2048>
        <<<dim3(16, 16, 4), dim3(256), 0, stream>>>(
            q_, k_, nullptr, E, nullptr, l, 0.03125f,
            6291456, 6291456, 4194304);

    // VWoT[z] = woT @ v[z]^T   [1024][2048] bf16 per batch  (512 blocks)
    gemm4w<EPI_BF16, 1024, 1024, 3072, 2048>
        <<<dim3(16, 8, 4), dim3(256), 0, stream>>>(
            woT, v_, nullptr, VWoT, nullptr, nullptr, 1.f,
            0, 6291456, 2097152);

    // out[z] = (E[z] @ VWoT[z]^T) / l + bo   fp32 [2048][1024]  (512 blocks)
    gemm4w<EPI_PVOUT, 2048, 2048, 2048, 1024>
        <<<dim3(8, 16, 4), dim3(256), 0, stream>>>(
            E, VWoT, bo, nullptr, out, l, 1.f,
            4194304, 2097152, 2097152);
}

// Round 8
// 274.071 us; speedup vs baseline: 2.9174x; 1.1256x over previous
//
#include <hip/hip_runtime.h>

// Self-attention fwd: B=4, S=2048, D=1024, single head.
// Round 16 = R13 (best passing, 273.9us) + ONE change: entry-phase stagger.
//   R15's frag read-ahead spilled (needs ~210 VGPR, allocator gave 128;
//   scratch traffic visible as WRITE 49->64MB). Reverted.
//   R13's limiter: 3000 cyc/CU-K-tile = LDS(~2050) + MFMA(1241) in exact
//   series at 2 blocks/CU. Hypothesis: co-resident blocks start synchronized
//   and in-phase contention is a stable equilibrium (both read -> both get
//   half LDS BW -> both stretch -> stay synced). Anti-phase is also stable
//   and ~33% faster (one block reads at full BW while the other MFMAs).
//   Fix: block-ID-dependent s_sleep chain at entry (~0/450/900/1350 cyc by
//   lin&3) to seed anti-phase. Sleep-only => zero correctness risk.
// Everything else byte-identical to R13 (grids, epilogues, swizzle, layout).
//
// ws layout (bf16-element offsets over (u16*)d_ws):
//   xb    @ 0          (8388608)   <- VWoT after QKV (xb dead)  [b][do][s]
//   qkv   @ 8388608    (25165824)  [8192][3072] (q|k|v interleaved by col)
//   E     @ 33554432   (16777216)  exp(logits) bf16
//   wqkvT @ 50331648   (3145728)   [3072][1024]  (wqT|wkT|wvT)
//   woT   @ 53477376   (1048576)
//   bqkv  @ 54525952   (6144 u16 = 3072 fp32)
//   l     @ 54532096   (16384 u16 = 8192 fp32 row sums)   end = 109.1 MB

typedef unsigned short u16;
typedef short bf16x8 __attribute__((ext_vector_type(8)));
typedef float f32x4 __attribute__((ext_vector_type(4)));

#define SEQ 2048
#define DIM 1024

__device__ __forceinline__ u16 f2bf(float f) {
    unsigned u = __builtin_bit_cast(unsigned, f);
    u += 0x7fffu + ((u >> 16) & 1u);
    return (u16)(u >> 16);
}

// async 16B global -> LDS (wave-uniform LDS base + lane*16 by construction)
__device__ __forceinline__ void async16(void* lds, const void* gmem) {
    __builtin_amdgcn_global_load_lds(
        (const __attribute__((address_space(1))) void*)gmem,
        (__attribute__((address_space(3))) void*)lds, 16, 0, 0);
}

#define FENCE() asm volatile("" ::: "memory")

// ---------------------------------------------------------------------------
// cast x fp32 -> bf16 (blocks 0..8191); bias concat + zero l (blocks 8192+)
__global__ __launch_bounds__(256) void cast_x_kernel(
    const float* __restrict__ x, u16* __restrict__ xb,
    const float* __restrict__ bq, const float* __restrict__ bk,
    const float* __restrict__ bv, float* __restrict__ bqkv,
    float* __restrict__ l)
{
    const int b = blockIdx.x;
    if (b < 8192) {
        const int idx = b * 256 + threadIdx.x;
        float4 v = ((const float4*)x)[idx];
        ushort4 o;
        o.x = f2bf(v.x); o.y = f2bf(v.y); o.z = f2bf(v.z); o.w = f2bf(v.w);
        ((ushort4*)xb)[idx] = o;
    } else {
        const int i = (b - 8192) * 256 + threadIdx.x;   // 0..11263
        if (i < 3072)
            bqkv[i] = (i < 1024) ? bq[i] : (i < 2048) ? bk[i - 1024] : bv[i - 2048];
        else if (i < 3072 + 8192)
            l[i - 3072] = 0.f;
    }
}

// transpose+cast all four 1024x1024 fp32 weights -> bf16 WT[n][k]; z picks W.
__global__ __launch_bounds__(256) void transpose_cast_all(
    const float* __restrict__ W0, const float* __restrict__ W1,
    const float* __restrict__ W2, const float* __restrict__ W3,
    u16* __restrict__ Tqkv, u16* __restrict__ To)
{
    __shared__ float tile[32][33];
    const int z = blockIdx.z;
    const float* W = (z == 0) ? W0 : (z == 1) ? W1 : (z == 2) ? W2 : W3;
    u16* T = (z < 3) ? (Tqkv + (size_t)z * 1048576) : To;

    const int bx = blockIdx.x * 32, by = blockIdx.y * 32;
    const int tx = threadIdx.x, ty = threadIdx.y;
    #pragma unroll
    for (int r = 0; r < 4; ++r)
        tile[ty + r * 8][tx] = W[(size_t)(by + ty + r * 8) * DIM + bx + tx];
    __syncthreads();
    #pragma unroll
    for (int r = 0; r < 4; ++r) {
        const float v = tile[tx][ty + r * 8];   // = W[by+tx][bx+ty+r*8]
        T[(size_t)(bx + ty + r * 8) * DIM + by + tx] = f2bf(v);
    }
}

// ---------------------------------------------------------------------------
// 128x128-tile 4-wave GEMM: A[M,K] @ Bt[N,K]^T. 2 blocks/CU (64 KiB LDS).
#define EPI_BF16BIAS 0  // bf16 store of a+bias[col]
#define EPI_BF16     1  // bf16 store of a
#define EPI_ELOGIT   2  // store exp(a*scale) bf16 + atomic row sums into lsum
#define EPI_PVOUT    3  // fp32 store of a/lsum[row] + bias[col]

template<int EPI, int K, int LDA, int LDB, int LDC>
__global__ __launch_bounds__(256, 2) void gemm4w(
    const u16* __restrict__ A, const u16* __restrict__ Bt,
    const float* __restrict__ bias, u16* __restrict__ C,
    float* __restrict__ Cf, float* __restrict__ lsum,
    float scale, long sA, long sB, long sC)
{
    // [dbuf][mat(A/B)][128x64 bf16], 16 KB each = 64 KiB total.
    __shared__ u16 lds[2][2][8192];

    constexpr int NT = K / 64;      // 64-wide K tiles

    const int z = blockIdx.z;
    const int t = threadIdx.x;                 // 0..255
    const int wid = t >> 6, lane = t & 63;
    const int wm = wid >> 1, wn = wid & 1;     // wave tile: 64x64 at (wm,wn)
    const int lrow = lane & 15, quad = lane >> 4;
    const int m0 = blockIdx.y * 128, n0 = blockIdx.x * 128;

    // entry-phase stagger: seed anti-phase between co-resident blocks.
    // s_sleep(7) ~ 448 cyc; slots 0/1/2/3 -> ~0/450/900/1350 cyc.
    const int lin = blockIdx.x + gridDim.x * (blockIdx.y + gridDim.y * z);
    const int slot = lin & 3;
    if (slot > 0) __builtin_amdgcn_s_sleep(7);
    if (slot > 1) __builtin_amdgcn_s_sleep(7);
    if (slot > 2) __builtin_amdgcn_s_sleep(7);

    const u16* ABase = A  + (size_t)z * sA + (size_t)m0 * LDA;
    const u16* BBase = Bt + (size_t)z * sB + (size_t)n0 * LDB;

    // staging: 1024 16B chunks per 128x64 tile; thread owns 4 per mat. LDS
    // dest linear (global_load_lds constraint); global SOURCE chunk column is
    // pre-swizzled with the read involution chunk ^= (row&7)
    // (byte bits 4-6 ^= row bits 0-2; rows are 128 B).
    int srow[4], scolOff[4];
    #pragma unroll
    for (int p = 0; p < 4; ++p) {
        const int s = p * 256 + t, row = s >> 3, c8 = (s & 7) ^ (row & 7);
        srow[p] = row; scolOff[p] = c8 * 8;
    }

    auto stage = [&](int tile, int buf) {
        const int k0 = tile * 64;
        #pragma unroll
        for (int p = 0; p < 4; ++p) {
            const int s = p * 256 + t;
            async16(&lds[buf][0][s * 8],
                    ABase + (size_t)srow[p] * LDA + k0 + scolOff[p]);
        }
        #pragma unroll
        for (int p = 0; p < 4; ++p) {
            const int s = p * 256 + t;
            async16(&lds[buf][1][s * 8],
                    BBase + (size_t)srow[p] * LDB + k0 + scolOff[p]);
        }
    };

    f32x4 acc[4][4];
    #pragma unroll
    for (int i = 0; i < 4; ++i)
        #pragma unroll
        for (int j = 0; j < 4; ++j)
            acc[i][j] = (f32x4){0.f, 0.f, 0.f, 0.f};

    // swizzled ds_read of one 16x16x32 fragment (16B per lane)
    auto ldA1 = [&](int buf, int mi, int ks) -> bf16x8 {
        int b = (wm * 64 + mi * 16 + lrow) * 128 + ks * 64 + quad * 16;
        b ^= ((b >> 7) & 7) << 4;
        return *(const bf16x8*)((const char*)&lds[buf][0][0] + b);
    };
    auto ldB1 = [&](int buf, int ni, int ks) -> bf16x8 {
        int b = (wn * 64 + ni * 16 + lrow) * 128 + ks * 64 + quad * 16;
        b ^= ((b >> 7) & 7) << 4;
        return *(const bf16x8*)((const char*)&lds[buf][1][0] + b);
    };

    // ---- prologue: tiles 0,1 in flight (8 wave-loads each) ----
    stage(0, 0);
    stage(1, 1);

    #pragma unroll 1
    for (int T = 0; T < NT; ++T) {
        const int buf = T & 1;
        // retire tile T's 8 loads; keep T+1's 8 in flight (counted, not 0)
        if (T + 1 < NT) asm volatile("s_waitcnt vmcnt(8)" ::: "memory");
        else            asm volatile("s_waitcnt vmcnt(0)" ::: "memory");
        __builtin_amdgcn_s_barrier();

        #pragma unroll
        for (int ks = 0; ks < 2; ++ks) {
            bf16x8 aF[4], bF[4];
            #pragma unroll
            for (int mi = 0; mi < 4; ++mi) aF[mi] = ldA1(buf, mi, ks);
            #pragma unroll
            for (int ni = 0; ni < 4; ++ni) bF[ni] = ldB1(buf, ni, ks);
            __builtin_amdgcn_s_setprio(1);
            #pragma unroll
            for (int mi = 0; mi < 4; ++mi)
                #pragma unroll
                for (int ni = 0; ni < 4; ++ni)
                    acc[mi][ni] = __builtin_amdgcn_mfma_f32_16x16x32_bf16(
                        aF[mi], bF[ni], acc[mi][ni], 0, 0, 0);
            __builtin_amdgcn_s_setprio(0);
        }
        FENCE();
        __builtin_amdgcn_s_barrier();   // buf's reads drained -> safe to restage
        if (T + 2 < NT) stage(T + 2, buf);
    }

    // ---- epilogue ----
    u16*   Cz  = C  + (size_t)z * sC;
    float* Cfz = Cf ? Cf + (size_t)z * sC : nullptr;

    #pragma unroll
    for (int mi = 0; mi < 4; ++mi) {
        const int row = m0 + wm * 64 + mi * 16 + quad * 4;   // rows row..row+3
        if (EPI == EPI_BF16BIAS) {
            #pragma unroll
            for (int ni = 0; ni < 4; ++ni) {
                const int col = n0 + wn * 64 + ni * 16 + lrow;
                const float bb = bias[col];
                const f32x4 a = acc[mi][ni];
                #pragma unroll
                for (int r = 0; r < 4; ++r)
                    Cz[(size_t)(row + r) * LDC + col] = f2bf(a[r] + bb);
            }
        } else if (EPI == EPI_BF16) {
            #pragma unroll
            for (int ni = 0; ni < 4; ++ni) {
                const int col = n0 + wn * 64 + ni * 16 + lrow;
                const f32x4 a = acc[mi][ni];
                #pragma unroll
                for (int r = 0; r < 4; ++r)
                    Cz[(size_t)(row + r) * LDC + col] = f2bf(a[r]);
            }
        } else if (EPI == EPI_ELOGIT) {
            float rs[4] = {0.f, 0.f, 0.f, 0.f};
            #pragma unroll
            for (int ni = 0; ni < 4; ++ni) {
                const int col = n0 + wn * 64 + ni * 16 + lrow;
                const f32x4 a = acc[mi][ni];
                #pragma unroll
                for (int r = 0; r < 4; ++r) {
                    const float e = __expf(a[r] * scale);
                    Cz[(size_t)(row + r) * LDC + col] = f2bf(e);
                    rs[r] += e;
                }
            }
            #pragma unroll
            for (int r = 0; r < 4; ++r) {
                float s = rs[r];
                s += __shfl_xor(s, 1, 64);
                s += __shfl_xor(s, 2, 64);
                s += __shfl_xor(s, 4, 64);
                s += __shfl_xor(s, 8, 64);
                if (lrow == 0)
                    atomicAdd(&lsum[(size_t)z * 2048 + row + r], s);
            }
        } else { // EPI_PVOUT
            float linv[4];
            #pragma unroll
            for (int r = 0; r < 4; ++r)
                linv[r] = 1.0f / lsum[(size_t)z * 2048 + row + r];
            #pragma unroll
            for (int ni = 0; ni < 4; ++ni) {
                const int col = n0 + wn * 64 + ni * 16 + lrow;
                const float bb = bias[col];
                const f32x4 a = acc[mi][ni];
                #pragma unroll
                for (int r = 0; r < 4; ++r)
                    Cfz[(size_t)(row + r) * LDC + col] = a[r] * linv[r] + bb;
            }
        }
    }
}

// ---------------------------------------------------------------------------
extern "C" void kernel_launch(void* const* d_in, const int* in_sizes, int n_in,
                              void* d_out, int out_size, void* d_ws, size_t ws_size,
                              hipStream_t stream)
{
    const float* x  = (const float*)d_in[0];
    const float* wq = (const float*)d_in[1];
    const float* bq = (const float*)d_in[2];
    const float* wk = (const float*)d_in[3];
    const float* bk = (const float*)d_in[4];
    const float* wv = (const float*)d_in[5];
    const float* bv = (const float*)d_in[6];
    const float* wo = (const float*)d_in[7];
    const float* bo = (const float*)d_in[8];
    float* out = (float*)d_out;

    u16* w16   = (u16*)d_ws;
    u16* xb    = w16;
    u16* qkv   = w16 + 8388608;          // [8192][3072]; q|k|v at col 0/1024/2048
    u16* E     = w16 + 33554432;
    u16* wqkvT = w16 + 50331648;         // [3072][1024] = wqT|wkT|wvT
    u16* woT   = w16 + 53477376;
    float* bqkv = (float*)(w16 + 54525952);
    float* l    = (float*)(w16 + 54532096);
    u16* VWoT  = w16;                    // aliases xb (dead after QKV) [b][1024][2048]

    const u16* q_ = qkv;                 // LDA/LDB = 3072 views
    const u16* k_ = qkv + 1024;
    const u16* v_ = qkv + 2048;

    cast_x_kernel<<<8236, dim3(256), 0, stream>>>(x, xb, bq, bk, bv, bqkv, l);
    transpose_cast_all<<<dim3(32, 32, 4), dim3(32, 8), 0, stream>>>(
        wq, wk, wv, wo, wqkvT, woT);

    // fused QKV: qkv[8192,3072] = xb @ wqkvT^T + bqkv   (24x64 = 1536 blocks)
    gemm4w<EPI_BF16BIAS, 1024, 1024, 1024, 3072>
        <<<dim3(24, 64, 1), dim3(256), 0, stream>>>(
            xb, wqkvT, bqkv, qkv, nullptr, nullptr, 1.f, 0, 0, 0);

    // E[z] = exp((q[z] @ k[z]^T)/32) bf16, + row sums into l  (1024 blocks)
    gemm4w<EPI_ELOGIT, 1024, 3072, 3072, 2048>
        <<<dim3(16, 16, 4), dim3(256), 0, stream>>>(
            q_, k_, nullptr, E, nullptr, l, 0.03125f,
            6291456, 6291456, 4194304);

    // VWoT[z] = woT @ v[z]^T   [1024][2048] bf16 per batch  (512 blocks)
    gemm4w<EPI_BF16, 1024, 1024, 3072, 2048>
        <<<dim3(16, 8, 4), dim3(256), 0, stream>>>(
            woT, v_, nullptr, VWoT, nullptr, nullptr, 1.f,
            0, 6291456, 2097152);

    // out[z] = (E[z] @ VWoT[z]^T) / l + bo   fp32 [2048][1024]  (512 blocks)
    gemm4w<EPI_PVOUT, 2048, 2048, 2048, 1024>
        <<<dim3(8, 16, 4), dim3(256), 0, stream>>>(
            E, VWoT, bo, nullptr, out, l, 1.f,
            4194304, 2097152, 2097152);
}